// Round 9
// baseline (488.334 us; speedup 1.0000x reference)
//
#include <hip/hip_runtime.h>
#include <hip/hip_bf16.h>

#define BATCH 4
#define NPTS  4096
#define NPTS2 4096
#define CIN   128
#define DIM   64
#define KNN   20
#define UPF   2
#define HPOS  64
#define HATT  256
#define MOUT  8192
#define EPSF  1e-5f
#define QPB   3            // queries per attn block
#define BPB   1366         // ceil(4096/3) attn blocks per batch

typedef _Float16 h16x8 __attribute__((ext_vector_type(8)));
typedef _Float16 h16x4 __attribute__((ext_vector_type(4)));
typedef _Float16 h16x2 __attribute__((ext_vector_type(2)));
typedef float    f32x4 __attribute__((ext_vector_type(4)));

__device__ inline float rdlane(float v, int src) {
  return __int_as_float(__builtin_amdgcn_readlane(__float_as_int(v), src));
}

// Bit-exact distance: explicit fma DAG -> identical value in every use site.
__device__ __forceinline__ float distf(float qn, float m2x, float m2y, float m2z,
                                       float x, float y, float z) {
  float s = __fmaf_rn(x, x, qn);
  s = __fmaf_rn(y, y, s);
  s = __fmaf_rn(z, z, s);
  s = __fmaf_rn(m2x, x, s);
  s = __fmaf_rn(m2y, y, s);
  s = __fmaf_rn(m2z, z, s);
  return s;
}

// ---------------------------------------------------------------------------
// proj_q (unchanged)
// ---------------------------------------------------------------------------
__global__ __launch_bounds__(256) void proj_q(const float* __restrict__ x,
    const float* __restrict__ wq, const float* __restrict__ bq,
    float* __restrict__ q_t) {
  __shared__ float X[CIN][64];
  __shared__ float O[64][65];
  const int b  = blockIdx.x >> 6;
  const int n0 = (blockIdx.x & 63) * 64;
  const int t  = threadIdx.x;
  for (int l = t; l < CIN * 64; l += 256) {
    int c = l >> 6, i = l & 63;
    X[c][i] = x[(b * CIN + c) * NPTS + n0 + i];
  }
  __syncthreads();
  const int n_l = t & 63;
  const int w   = __builtin_amdgcn_readfirstlane(t >> 6);
  float acc[16];
#pragma unroll
  for (int i = 0; i < 16; ++i) acc[i] = bq[w * 16 + i];
  for (int c = 0; c < CIN; ++c) {
    float xv = X[c][n_l];
#pragma unroll
    for (int i = 0; i < 16; ++i) acc[i] += wq[(w * 16 + i) * CIN + c] * xv;
  }
#pragma unroll
  for (int i = 0; i < 16; ++i) O[n_l][w * 16 + i] = acc[i];
  __syncthreads();
  for (int l = t; l < 64 * 64; l += 256)
    q_t[(b * NPTS + n0 + (l >> 6)) * DIM + (l & 63)] = O[l >> 6][l & 63];
}

// ---------------------------------------------------------------------------
// proj_kv (unchanged)
// ---------------------------------------------------------------------------
__global__ __launch_bounds__(256) void proj_kv(const float* __restrict__ x,
    const float* __restrict__ wk, const float* __restrict__ bk,
    const float* __restrict__ wv, const float* __restrict__ bv,
    float* __restrict__ k_t, float* __restrict__ v_t) {
  __shared__ float X[CIN][64];
  __shared__ float O[64][65];
  const int b  = blockIdx.x >> 6;
  const int n0 = (blockIdx.x & 63) * 64;
  const int t  = threadIdx.x;
  for (int l = t; l < CIN * 64; l += 256) {
    int c = l >> 6, i = l & 63;
    X[c][i] = x[(b * CIN + c) * NPTS2 + n0 + i];
  }
  __syncthreads();
  const int n_l = t & 63;
  const int w   = __builtin_amdgcn_readfirstlane(t >> 6);
  float acck[16], accv[16];
#pragma unroll
  for (int i = 0; i < 16; ++i) { acck[i] = bk[w * 16 + i]; accv[i] = bv[w * 16 + i]; }
  for (int c = 0; c < CIN; ++c) {
    float xv = X[c][n_l];
#pragma unroll
    for (int i = 0; i < 16; ++i) {
      acck[i] += wk[(w * 16 + i) * CIN + c] * xv;
      accv[i] += wv[(w * 16 + i) * CIN + c] * xv;
    }
  }
#pragma unroll
  for (int i = 0; i < 16; ++i) O[n_l][w * 16 + i] = acck[i];
  __syncthreads();
  for (int l = t; l < 64 * 64; l += 256)
    k_t[(b * NPTS2 + n0 + (l >> 6)) * DIM + (l & 63)] = O[l >> 6][l & 63];
  __syncthreads();
#pragma unroll
  for (int i = 0; i < 16; ++i) O[n_l][w * 16 + i] = accv[i];
  __syncthreads();
  for (int l = t; l < 64 * 64; l += 256)
    v_t[(b * NPTS2 + n0 + (l >> 6)) * DIM + (l & 63)] = O[l >> 6][l & 63];
}

// ---------------------------------------------------------------------------
// knn v4 (unchanged): threshold + LDS append + bitonic pair sort.
// ---------------------------------------------------------------------------
__global__ __launch_bounds__(256) void knn_kernel(const float* __restrict__ pos1,
    const float* __restrict__ pos2, int* __restrict__ idxout) {
  __shared__ int   cntS[4];
  __shared__ float dbufS[4][64];
  __shared__ int   jbufS[4][64];
  const int lane = threadIdx.x & 63;
  const int wv   = threadIdx.x >> 6;
  const int g    = blockIdx.x * 4 + wv;
  const int b    = g >> 12;
  const int n    = g & (NPTS - 1);
  const float qx = pos1[(b * 3 + 0) * NPTS + n];
  const float qy = pos1[(b * 3 + 1) * NPTS + n];
  const float qz = pos1[(b * 3 + 2) * NPTS + n];
  const float qn = qx * qx + qy * qy + qz * qz;
  const float m2x = -2.0f * qx, m2y = -2.0f * qy, m2z = -2.0f * qz;
  const float* p2x = pos2 + (b * 3 + 0) * NPTS2;
  const float* p2y = pos2 + (b * 3 + 1) * NPTS2;
  const float* p2z = pos2 + (b * 3 + 2) * NPTS2;

  float mymin = 3.402823466e38f;
  for (int j0 = 0; j0 < NPTS2; j0 += 64) {
    int j = j0 + lane;
    float d = distf(qn, m2x, m2y, m2z, p2x[j], p2y[j], p2z[j]);
    mymin = fminf(mymin, d);
  }
  float v = mymin;
#pragma unroll
  for (int k = 2; k <= 64; k <<= 1) {
#pragma unroll
    for (int jj = k >> 1; jj >= 1; jj >>= 1) {
      float o = __shfl_xor(v, jj);
      bool up = ((lane & k) == 0);
      bool keepmin = (((lane & jj) == 0) == up);
      v = keepmin ? fminf(v, o) : fmaxf(v, o);
    }
  }
  const float T0 = rdlane(v, 19);

  if (lane == 0) cntS[wv] = 0;
  __syncthreads();

  for (int j0 = 0; j0 < NPTS2; j0 += 64) {
    int j = j0 + lane;
    float d = distf(qn, m2x, m2y, m2z, p2x[j], p2y[j], p2z[j]);
    if (d <= T0) {
      int slot = atomicAdd(&cntS[wv], 1);
      if (slot < 64) { dbufS[wv][slot] = d; jbufS[wv][slot] = j; }
    }
  }
  __syncthreads();

  const int cnt = cntS[wv];
  if (cnt <= 64) {
    float dk = (lane < cnt) ? dbufS[wv][lane] : 3.402823466e38f;
    int   jk = (lane < cnt) ? jbufS[wv][lane] : 0x7fffffff;
#pragma unroll
    for (int k = 2; k <= 64; k <<= 1) {
#pragma unroll
      for (int jj = k >> 1; jj >= 1; jj >>= 1) {
        float od = __shfl_xor(dk, jj);
        int   oj = __shfl_xor(jk, jj);
        bool mineSm = (dk < od) || (dk == od && jk < oj);
        bool up = ((lane & k) == 0);
        bool keepmin = (((lane & jj) == 0) == up);
        bool takeOther = (keepmin != mineSm);
        dk = takeOther ? od : dk;
        jk = takeOther ? oj : jk;
      }
    }
    if (lane < KNN) idxout[(b * NPTS + n) * KNN + lane] = jk;
  } else {
    float dl = 3.402823466e38f;
    int   il = 0;
    for (int j0 = 0; j0 < NPTS2; j0 += 64) {
      int j = j0 + lane;
      float d = distf(qn, m2x, m2y, m2z, p2x[j], p2y[j], p2z[j]);
      float T = rdlane(dl, 19);
      unsigned long long m = __ballot(d < T);
      while (m) {
        int src = __ffsll(m) - 1;
        m &= m - 1;
        float dd = rdlane(d, src);
        float T2 = rdlane(dl, 19);
        if (dd < T2) {
          int jj2 = j0 + src;
          float pd = __shfl_up(dl, 1);
          int   pi = __shfl_up(il, 1);
          if (dl > dd) {
            if (lane == 0 || pd <= dd) { dl = dd; il = jj2; }
            else                       { dl = pd; il = pi; }
          }
        }
      }
    }
    if (lane < KNN) idxout[(b * NPTS + n) * KNN + lane] = il;
  }
}

// ---------------------------------------------------------------------------
// pack_weights (unchanged from R8): BN folded into weights/biases.
// ---------------------------------------------------------------------------
__global__ __launch_bounds__(256) void pack_weights(
    const float* __restrict__ aw1, const float* __restrict__ awt,
    const float* __restrict__ pw2,
    const float* __restrict__ ag,  const float* __restrict__ av,
    const float* __restrict__ abt2, const float* __restrict__ am,
    const float* __restrict__ abt,
    const float* __restrict__ pg,  const float* __restrict__ pv,
    const float* __restrict__ pbt, const float* __restrict__ pm,
    const float* __restrict__ ab1, const float* __restrict__ pb1,
    const float* __restrict__ pw1,
    _Float16* __restrict__ aw1h, _Float16* __restrict__ awtP,
    _Float16* __restrict__ pw2h, float* __restrict__ abtX,
    float* __restrict__ ab1f, float* __restrict__ pw1f,
    float* __restrict__ pb1f) {
  int i = blockIdx.x * 256 + threadIdx.x;
  if (i < 16384) {
    int j = i >> 6;
    float inv = ag[j] / sqrtf(av[j] + EPSF);
    aw1h[i] = (_Float16)(aw1[i] * inv);
  }
  if (i < 32768) {
    int orr = i >> 8, j = i & 255;
    awtP[i] = (_Float16)awt[j * 128 + orr];
  }
  if (i < 4096) pw2h[i] = (_Float16)pw2[i];
  if (i < 256) {
    float inv = ag[i] / sqrtf(av[i] + EPSF);
    ab1f[i] = ab1[i] * inv + (abt2[i] - am[i] * inv);
  }
  if (i < 192) {
    int hc = i / 3;
    float inv = pg[hc] / sqrtf(pv[hc] + EPSF);
    pw1f[i] = pw1[i] * inv;
  }
  if (i < 128) abtX[i] = abt[i >> 1];
  if (i < 64) {
    float inv = pg[i] / sqrtf(pv[i] + EPSF);
    pb1f[i] = pb1[i] * inv + (pbt[i] - pm[i] * inv);
  }
}

// ---------------------------------------------------------------------------
// attn_mfma (R9): quarter-split C/D + 3-region LDS aliasing -> 26880 B ->
// 6 blocks/CU. Region lifetimes:
//   R0 [0    , 9216): h1B 64x72 f16 (P1->A); hB 64x72 f16 (B->bs-load);
//                     aLq 64x72 f16 (C->D, per quarter)
//   R1 [9216 ,17920): peL 64x68 f16 (A->B); lgc 64x68 f16 (epi->E)
//   SJ [17920,18176): sj 64 int (P0->P1)
//   VG [18176,26880): vgB 64x68 f16 (B->E)
// hB is consumed into bs[2][4] registers before aLq overwrites it (extra
// barrier after the register load).
// ---------------------------------------------------------------------------
#define SM_H1B   0
#define SM_HB    0
#define SM_ALQ   0
#define SM_PEL   9216
#define SM_LGC   9216
#define SM_SJ    17920
#define SM_VGB   18176

__global__ __launch_bounds__(256, 6) void attn_mfma(
    const float* __restrict__ q_t, const float* __restrict__ k_t,
    const float* __restrict__ v_t, const int* __restrict__ idx,
    const float* __restrict__ pos1, const float* __restrict__ pos2,
    const float* __restrict__ pw1f, const float* __restrict__ pb1f,
    const _Float16* __restrict__ pw2h, const float* __restrict__ pb2,
    const _Float16* __restrict__ aw1h, const float* __restrict__ ab1f,
    const _Float16* __restrict__ awtP, const float* __restrict__ abtX,
    float* __restrict__ agg) {
  __shared__ __align__(16) char smem[26880];
  const int b  = blockIdx.x / BPB;
  const int n0 = (blockIdx.x - b * BPB) * QPB;
  const int t  = threadIdx.x;
  const int lane = t & 63;
  const int w  = t >> 6;        // wave id
  const int r  = lane & 15;     // tile lane index
  const int q4 = lane >> 4;     // quad

  int* sj = (int*)(smem + SM_SJ);

  // Phase 0: neighbor indices (invalid cols -> 0)
  if (t < 64) {
    int col = t;
    int p = col / 20, kk = col - p * 20;
    int nq = n0 + p;
    int vI = 0;
    if (p < QPB && nq < NPTS) vI = idx[(b * NPTS + nq) * KNN + kk];
    sj[col] = vI;
  }
  __syncthreads();

  // Prefetch q/k/v gather rows into registers (hide global latency)
  const int colB = t & 63, cgB = t >> 6;
  const int pB = colB / 20;
  const bool okB = (pB < QPB) && (n0 + pB < NPTS);
  f32x4 qv4[4], kv4[4], vv4[4];
  {
    int jB  = sj[colB];
    int nqB = okB ? (n0 + pB) : 0;
    const float* qrow = q_t + ((size_t)(b * NPTS  + nqB)) * DIM + cgB * 16;
    const float* krow = k_t + ((size_t)(b * NPTS2 + jB))  * DIM + cgB * 16;
    const float* vrow = v_t + ((size_t)(b * NPTS2 + jB))  * DIM + cgB * 16;
#pragma unroll
    for (int u = 0; u < 4; ++u) {
      qv4[u] = *(const f32x4*)(qrow + u * 4);
      kv4[u] = *(const f32x4*)(krow + u * 4);
      vv4[u] = *(const f32x4*)(vrow + u * 4);
    }
  }

  // Phase 1: pos-MLP hidden (BN folded) -> h1B f16 [col][hc] stride 72
  {
    int col = t & 63, hg = t >> 6;
    int p = col / 20;
    int j = sj[col];
    bool okc = (p < QPB) && (n0 + p < NPTS);
    float p0 = 0.f, p1 = 0.f, p2 = 0.f;
    if (okc) {
      int nq = n0 + p;
      p0 = pos1[(b * 3 + 0) * NPTS + nq] - pos2[(b * 3 + 0) * NPTS2 + j];
      p1 = pos1[(b * 3 + 1) * NPTS + nq] - pos2[(b * 3 + 1) * NPTS2 + j];
      p2 = pos1[(b * 3 + 2) * NPTS + nq] - pos2[(b * 3 + 2) * NPTS2 + j];
    }
#pragma unroll
    for (int ii = 0; ii < 16; ii += 2) {
      int hc = hg * 16 + ii;
      float v0 = pb1f[hc]     + pw1f[hc*3]   * p0 + pw1f[hc*3+1] * p1 + pw1f[hc*3+2] * p2;
      float v1 = pb1f[hc + 1] + pw1f[hc*3+3] * p0 + pw1f[hc*3+4] * p1 + pw1f[hc*3+5] * p2;
      v0 = fmaxf(v0, 0.f);
      v1 = fmaxf(v1, 0.f);
      if (!okc) { v0 = 0.f; v1 = 0.f; }
      h16x2 pk = {(_Float16)v0, (_Float16)v1};
      *(h16x2*)(smem + SM_H1B + ((col * 72 + hc) * 2)) = pk;
    }
  }
  __syncthreads();

  // Phase A: GEMM0 pe = pw2 @ h1 (+pb2) -> peL f16 [col][o] stride 68
  {
    h16x8 a0[2];
#pragma unroll
    for (int ks = 0; ks < 2; ++ks)
      a0[ks] = *(const h16x8*)&pw2h[(w * 16 + r) * 64 + ks * 32 + q4 * 8];
    f32x4 acc[4];
#pragma unroll
    for (int nt = 0; nt < 4; ++nt) acc[nt] = (f32x4){0.f, 0.f, 0.f, 0.f};
#pragma unroll
    for (int ks = 0; ks < 2; ++ks)
#pragma unroll
      for (int nt = 0; nt < 4; ++nt) {
        h16x8 bv = *(h16x8*)(smem + SM_H1B + ((nt * 16 + r) * 72 + ks * 32 + q4 * 8) * 2);
        acc[nt] = __builtin_amdgcn_mfma_f32_16x16x32_f16(a0[ks], bv, acc[nt], 0, 0, 0);
      }
    int o0 = w * 16 + q4 * 4;
    f32x4 pbv = *(const f32x4*)&pb2[o0];
#pragma unroll
    for (int nt = 0; nt < 4; ++nt) {
      f32x4 vv = acc[nt] + pbv;
      h16x4 pk = {(_Float16)vv[0], (_Float16)vv[1], (_Float16)vv[2], (_Float16)vv[3]};
      *(h16x4*)(smem + SM_PEL + ((nt * 16 + r) * 68 + o0) * 2) = pk;
    }
  }
  __syncthreads();

  // Phase B: combine prefetched q/k/v with pe -> hB (region0), vgB (f16)
  {
#pragma unroll
    for (int u = 0; u < 4; ++u) {
      int c0 = cgB * 16 + u * 4;
      h16x4 peh = *(h16x4*)(smem + SM_PEL + (colB * 68 + c0) * 2);
      f32x4 pe = {(float)peh[0], (float)peh[1], (float)peh[2], (float)peh[3]};
      f32x4 hv = qv4[u] - kv4[u] + pe;
      f32x4 gv = vv4[u] + pe;
      if (!okB) { hv = (f32x4){0.f,0.f,0.f,0.f}; gv = hv; }
      h16x4 hp = {(_Float16)hv[0], (_Float16)hv[1], (_Float16)hv[2], (_Float16)hv[3]};
      h16x4 gp = {(_Float16)gv[0], (_Float16)gv[1], (_Float16)gv[2], (_Float16)gv[3]};
      *(h16x4*)(smem + SM_HB  + (colB * 72 + c0) * 2) = hp;
      *(h16x4*)(smem + SM_VGB + (colB * 68 + c0) * 2) = gp;
    }
  }
  __syncthreads();

  // bs register load: h fragments (B-operand) for all 4 col tiles
  h16x8 bs[2][4];
#pragma unroll
  for (int ks = 0; ks < 2; ++ks)
#pragma unroll
    for (int nt = 0; nt < 4; ++nt)
      bs[ks][nt] = *(h16x8*)(smem + SM_HB + ((nt * 16 + r) * 72 + ks * 32 + q4 * 8) * 2);
  __syncthreads();   // hB fully consumed; region0 free for aLq

  // Phases C+D over four j-quarters (64 j's each). D accumulators in regs.
  f32x4 accD[2][4];
#pragma unroll
  for (int h = 0; h < 2; ++h)
#pragma unroll
    for (int nt = 0; nt < 4; ++nt) accD[h][nt] = (f32x4){0.f, 0.f, 0.f, 0.f};

#pragma unroll
  for (int quar = 0; quar < 4; ++quar) {
    // C-quarter: a = relu(aw1'@h + ab1'), 1 M-tile per wave
    {
      int mt = quar * 4 + w;
      h16x8 af0 = *(const h16x8*)&aw1h[(mt * 16 + r) * 64 + q4 * 8];
      h16x8 af1 = *(const h16x8*)&aw1h[(mt * 16 + r) * 64 + 32 + q4 * 8];
      f32x4 acc[4];
#pragma unroll
      for (int nt = 0; nt < 4; ++nt) acc[nt] = (f32x4){0.f, 0.f, 0.f, 0.f};
#pragma unroll
      for (int nt = 0; nt < 4; ++nt)
        acc[nt] = __builtin_amdgcn_mfma_f32_16x16x32_f16(af0, bs[0][nt], acc[nt], 0, 0, 0);
#pragma unroll
      for (int nt = 0; nt < 4; ++nt)
        acc[nt] = __builtin_amdgcn_mfma_f32_16x16x32_f16(af1, bs[1][nt], acc[nt], 0, 0, 0);
      int j0  = mt * 16 + q4 * 4;            // global j
      int jq0 = j0 - quar * 64;              // within quarter [0,64)
      f32x4 b1 = *(const f32x4*)&ab1f[j0];
#pragma unroll
      for (int nt = 0; nt < 4; ++nt) {
        int col = nt * 16 + r;
        float v0 = fmaxf(acc[nt][0] + b1[0], 0.f);
        float v1 = fmaxf(acc[nt][1] + b1[1], 0.f);
        float v2 = fmaxf(acc[nt][2] + b1[2], 0.f);
        float v3 = fmaxf(acc[nt][3] + b1[3], 0.f);
        h16x4 pk = {(_Float16)v0, (_Float16)v1, (_Float16)v2, (_Float16)v3};
        *(h16x4*)(smem + SM_ALQ + (col * 72 + jq0) * 2) = pk;
      }
    }
    __syncthreads();

    // D-quarter: accumulate logits over this quarter's K (2 x 32)
#pragma unroll
    for (int ks2 = 0; ks2 < 2; ++ks2) {
      h16x8 bsv[4];
#pragma unroll
      for (int nt = 0; nt < 4; ++nt)
        bsv[nt] = *(h16x8*)(smem + SM_ALQ + ((nt * 16 + r) * 72 + ks2 * 32 + q4 * 8) * 2);
      int ksg = quar * 2 + ks2;
#pragma unroll
      for (int h = 0; h < 2; ++h) {
        int mt2 = w * 2 + h;
        h16x8 af = *(const h16x8*)&awtP[(mt2 * 16 + r) * 256 + ksg * 32 + q4 * 8];
#pragma unroll
        for (int nt = 0; nt < 4; ++nt)
          accD[h][nt] = __builtin_amdgcn_mfma_f32_16x16x32_f16(af, bsv[nt], accD[h][nt], 0, 0, 0);
      }
    }
    __syncthreads();   // before next quarter's aLq rewrite
  }

  // Phase D epilogue + E: 2 half-rounds of (write lgc, softmax+agg)
  {
    const int li0 = w * 16 + q4 * 4;
#pragma unroll
    for (int h = 0; h < 2; ++h) {
      if (h) __syncthreads();   // E(h=0) done reading lgc
      int orr0 = (w * 2 + h) * 16 + q4 * 4;
      f32x4 ab = *(const f32x4*)&abtX[orr0];
#pragma unroll
      for (int nt = 0; nt < 4; ++nt) {
        int col = nt * 16 + r;
        if (col < QPB * KNN) {
          f32x4 vv = accD[h][nt] + ab;
          h16x4 pk = {(_Float16)vv[0], (_Float16)vv[1], (_Float16)vv[2], (_Float16)vv[3]};
          *(h16x4*)(smem + SM_LGC + (col * 68 + li0) * 2) = pk;
        }
      }
      __syncthreads();
      if (t < 64 * QPB) {
        int li = t & 63, p = t >> 6;
        if (n0 + p < NPTS) {
          int w2 = li >> 4;
          int orr = w2 * 32 + h * 16 + (li & 15);
          int o = orr >> 1, rb = orr & 1;
          float L[KNN];
#pragma unroll
          for (int kk = 0; kk < KNN; ++kk)
            L[kk] = (float)*(_Float16*)(smem + SM_LGC + (((p * 20 + kk) * 68 + li) * 2));
          float mx = L[0];
#pragma unroll
          for (int kk = 1; kk < KNN; ++kk) mx = fmaxf(mx, L[kk]);
          float s = 0.f;
#pragma unroll
          for (int kk = 0; kk < KNN; ++kk) { L[kk] = __expf(L[kk] - mx); s += L[kk]; }
          float rs = 1.0f / s;
          float a = 0.f;
#pragma unroll
          for (int kk = 0; kk < KNN; ++kk) {
            _Float16 gv = *(_Float16*)(smem + SM_VGB + (((p * 20 + kk) * 68 + o) * 2));
            a += L[kk] * (float)gv;
          }
          agg[(((size_t)(b * NPTS + n0 + p)) * UPF + rb) * DIM + o] = a * rs;
        }
      }
    }
  }
}

// ---------------------------------------------------------------------------
// out_proj (unchanged)
// ---------------------------------------------------------------------------
__global__ __launch_bounds__(256) void out_proj(const float* __restrict__ agg,
    const float* __restrict__ we, const float* __restrict__ be,
    const float* __restrict__ query, float* __restrict__ out) {
  __shared__ float A[64][65];
  const int b  = blockIdx.x >> 7;
  const int m0 = (blockIdx.x & 127) * 64;
  const int t  = threadIdx.x;
  for (int l = t; l < 64 * 64; l += 256) {
    int row = l >> 6, c = l & 63;
    A[row][c] = agg[(b * MOUT + m0 + row) * DIM + c];
  }
  __syncthreads();
  const int m_l = t & 63;
  const int w   = __builtin_amdgcn_readfirstlane(t >> 6);
  float acc[32];
#pragma unroll
  for (int i = 0; i < 32; ++i) acc[i] = 0.f;
  for (int c = 0; c < DIM; ++c) {
    float a = A[m_l][c];
#pragma unroll
    for (int i = 0; i < 32; ++i) acc[i] += we[(w * 32 + i) * DIM + c] * a;
  }
  const int m = m0 + m_l;
#pragma unroll
  for (int i = 0; i < 32; ++i) {
    int o = w * 32 + i;
    out[(b * CIN + o) * MOUT + m] = acc[i] + be[o] + query[(b * CIN + o) * NPTS + (m >> 1)];
  }
}

// ---------------------------------------------------------------------------
extern "C" void kernel_launch(void* const* d_in, const int* in_sizes, int n_in,
                              void* d_out, int out_size, void* d_ws, size_t ws_size,
                              hipStream_t stream) {
  (void)in_sizes; (void)n_in; (void)out_size; (void)ws_size;
  const float* pos1     = (const float*)d_in[0];
  const float* query    = (const float*)d_in[1];
  const float* pos2     = (const float*)d_in[2];
  const float* key_feat = (const float*)d_in[3];
  const float* wq  = (const float*)d_in[4];
  const float* bq  = (const float*)d_in[5];
  const float* wk  = (const float*)d_in[6];
  const float* bk  = (const float*)d_in[7];
  const float* wv  = (const float*)d_in[8];
  const float* bv  = (const float*)d_in[9];
  const float* pw1 = (const float*)d_in[10];
  const float* pb1 = (const float*)d_in[11];
  const float* pg  = (const float*)d_in[12];
  const float* pbt = (const float*)d_in[13];
  const float* pm  = (const float*)d_in[14];
  const float* pv  = (const float*)d_in[15];
  const float* pw2 = (const float*)d_in[16];
  const float* pb2 = (const float*)d_in[17];
  const float* aw1 = (const float*)d_in[18];
  const float* ab1 = (const float*)d_in[19];
  const float* ag  = (const float*)d_in[20];
  const float* abt2= (const float*)d_in[21];
  const float* am  = (const float*)d_in[22];
  const float* av  = (const float*)d_in[23];
  const float* awt = (const float*)d_in[24];
  const float* abt = (const float*)d_in[25];
  const float* we  = (const float*)d_in[26];
  const float* be  = (const float*)d_in[27];

  float* ws   = (float*)d_ws;
  float* q_t  = ws;
  float* k_t  = q_t + BATCH * NPTS * DIM;
  float* v_t  = k_t + BATCH * NPTS2 * DIM;
  float* aggb = v_t + BATCH * NPTS2 * DIM;
  int*   idxb = (int*)(aggb + BATCH * MOUT * DIM);
  _Float16* aw1h = (_Float16*)(idxb + BATCH * NPTS * KNN);
  _Float16* awtP = aw1h + HATT * DIM;
  _Float16* pw2h = awtP + 128 * HATT;
  float* abtX    = (float*)(pw2h + DIM * HPOS);
  float* ab1f    = abtX + 128;
  float* pw1f    = ab1f + HATT;
  float* pb1f    = pw1f + HPOS * 3;

  pack_weights<<<128, 256, 0, stream>>>(aw1, awt, pw2, ag, av, abt2, am, abt,
      pg, pv, pbt, pm, ab1, pb1, pw1,
      aw1h, awtP, pw2h, abtX, ab1f, pw1f, pb1f);
  proj_q <<<BATCH * (NPTS / 64), 256, 0, stream>>>(query, wq, bq, q_t);
  proj_kv<<<BATCH * (NPTS2 / 64), 256, 0, stream>>>(key_feat, wk, bk, wv, bv, k_t, v_t);
  knn_kernel<<<BATCH * NPTS / 4, 256, 0, stream>>>(pos1, pos2, idxb);
  attn_mfma<<<BATCH * BPB, 256, 0, stream>>>(q_t, k_t, v_t, idxb, pos1, pos2,
      pw1f, pb1f, pw2h, pb2, aw1h, ab1f, awtP, abtX, aggb);
  out_proj<<<BATCH * (MOUT / 64), 256, 0, stream>>>(aggb, we, be, query, (float*)d_out);
}

// Round 10
// 384.502 us; speedup vs baseline: 1.2700x; 1.2700x over previous
//
#include <hip/hip_runtime.h>
#include <hip/hip_bf16.h>

#define BATCH 4
#define NPTS  4096
#define NPTS2 4096
#define CIN   128
#define DIM   64
#define KNN   20
#define UPF   2
#define HPOS  64
#define HATT  256
#define MOUT  8192
#define EPSF  1e-5f
#define QPB   3            // queries per attn block
#define BPB   1366         // ceil(4096/3) attn blocks per batch

typedef _Float16 h16x8 __attribute__((ext_vector_type(8)));
typedef _Float16 h16x4 __attribute__((ext_vector_type(4)));
typedef _Float16 h16x2 __attribute__((ext_vector_type(2)));
typedef float    f32x4 __attribute__((ext_vector_type(4)));

__device__ inline float rdlane(float v, int src) {
  return __int_as_float(__builtin_amdgcn_readlane(__float_as_int(v), src));
}

// Bit-exact distance: explicit fma DAG -> identical value in every use site.
__device__ __forceinline__ float distf(float qn, float m2x, float m2y, float m2z,
                                       float x, float y, float z) {
  float s = __fmaf_rn(x, x, qn);
  s = __fmaf_rn(y, y, s);
  s = __fmaf_rn(z, z, s);
  s = __fmaf_rn(m2x, x, s);
  s = __fmaf_rn(m2y, y, s);
  s = __fmaf_rn(m2z, z, s);
  return s;
}

// ---------------------------------------------------------------------------
// proj_q (unchanged)
// ---------------------------------------------------------------------------
__global__ __launch_bounds__(256) void proj_q(const float* __restrict__ x,
    const float* __restrict__ wq, const float* __restrict__ bq,
    float* __restrict__ q_t) {
  __shared__ float X[CIN][64];
  __shared__ float O[64][65];
  const int b  = blockIdx.x >> 6;
  const int n0 = (blockIdx.x & 63) * 64;
  const int t  = threadIdx.x;
  for (int l = t; l < CIN * 64; l += 256) {
    int c = l >> 6, i = l & 63;
    X[c][i] = x[(b * CIN + c) * NPTS + n0 + i];
  }
  __syncthreads();
  const int n_l = t & 63;
  const int w   = __builtin_amdgcn_readfirstlane(t >> 6);
  float acc[16];
#pragma unroll
  for (int i = 0; i < 16; ++i) acc[i] = bq[w * 16 + i];
  for (int c = 0; c < CIN; ++c) {
    float xv = X[c][n_l];
#pragma unroll
    for (int i = 0; i < 16; ++i) acc[i] += wq[(w * 16 + i) * CIN + c] * xv;
  }
#pragma unroll
  for (int i = 0; i < 16; ++i) O[n_l][w * 16 + i] = acc[i];
  __syncthreads();
  for (int l = t; l < 64 * 64; l += 256)
    q_t[(b * NPTS + n0 + (l >> 6)) * DIM + (l & 63)] = O[l >> 6][l & 63];
}

// ---------------------------------------------------------------------------
// proj_kv (unchanged)
// ---------------------------------------------------------------------------
__global__ __launch_bounds__(256) void proj_kv(const float* __restrict__ x,
    const float* __restrict__ wk, const float* __restrict__ bk,
    const float* __restrict__ wv, const float* __restrict__ bv,
    float* __restrict__ k_t, float* __restrict__ v_t) {
  __shared__ float X[CIN][64];
  __shared__ float O[64][65];
  const int b  = blockIdx.x >> 6;
  const int n0 = (blockIdx.x & 63) * 64;
  const int t  = threadIdx.x;
  for (int l = t; l < CIN * 64; l += 256) {
    int c = l >> 6, i = l & 63;
    X[c][i] = x[(b * CIN + c) * NPTS2 + n0 + i];
  }
  __syncthreads();
  const int n_l = t & 63;
  const int w   = __builtin_amdgcn_readfirstlane(t >> 6);
  float acck[16], accv[16];
#pragma unroll
  for (int i = 0; i < 16; ++i) { acck[i] = bk[w * 16 + i]; accv[i] = bv[w * 16 + i]; }
  for (int c = 0; c < CIN; ++c) {
    float xv = X[c][n_l];
#pragma unroll
    for (int i = 0; i < 16; ++i) {
      acck[i] += wk[(w * 16 + i) * CIN + c] * xv;
      accv[i] += wv[(w * 16 + i) * CIN + c] * xv;
    }
  }
#pragma unroll
  for (int i = 0; i < 16; ++i) O[n_l][w * 16 + i] = acck[i];
  __syncthreads();
  for (int l = t; l < 64 * 64; l += 256)
    k_t[(b * NPTS2 + n0 + (l >> 6)) * DIM + (l & 63)] = O[l >> 6][l & 63];
  __syncthreads();
#pragma unroll
  for (int i = 0; i < 16; ++i) O[n_l][w * 16 + i] = accv[i];
  __syncthreads();
  for (int l = t; l < 64 * 64; l += 256)
    v_t[(b * NPTS2 + n0 + (l >> 6)) * DIM + (l & 63)] = O[l >> 6][l & 63];
}

// ---------------------------------------------------------------------------
// knn v4 (unchanged): threshold + LDS append + bitonic pair sort.
// ---------------------------------------------------------------------------
__global__ __launch_bounds__(256) void knn_kernel(const float* __restrict__ pos1,
    const float* __restrict__ pos2, int* __restrict__ idxout) {
  __shared__ int   cntS[4];
  __shared__ float dbufS[4][64];
  __shared__ int   jbufS[4][64];
  const int lane = threadIdx.x & 63;
  const int wv   = threadIdx.x >> 6;
  const int g    = blockIdx.x * 4 + wv;
  const int b    = g >> 12;
  const int n    = g & (NPTS - 1);
  const float qx = pos1[(b * 3 + 0) * NPTS + n];
  const float qy = pos1[(b * 3 + 1) * NPTS + n];
  const float qz = pos1[(b * 3 + 2) * NPTS + n];
  const float qn = qx * qx + qy * qy + qz * qz;
  const float m2x = -2.0f * qx, m2y = -2.0f * qy, m2z = -2.0f * qz;
  const float* p2x = pos2 + (b * 3 + 0) * NPTS2;
  const float* p2y = pos2 + (b * 3 + 1) * NPTS2;
  const float* p2z = pos2 + (b * 3 + 2) * NPTS2;

  float mymin = 3.402823466e38f;
  for (int j0 = 0; j0 < NPTS2; j0 += 64) {
    int j = j0 + lane;
    float d = distf(qn, m2x, m2y, m2z, p2x[j], p2y[j], p2z[j]);
    mymin = fminf(mymin, d);
  }
  float v = mymin;
#pragma unroll
  for (int k = 2; k <= 64; k <<= 1) {
#pragma unroll
    for (int jj = k >> 1; jj >= 1; jj >>= 1) {
      float o = __shfl_xor(v, jj);
      bool up = ((lane & k) == 0);
      bool keepmin = (((lane & jj) == 0) == up);
      v = keepmin ? fminf(v, o) : fmaxf(v, o);
    }
  }
  const float T0 = rdlane(v, 19);

  if (lane == 0) cntS[wv] = 0;
  __syncthreads();

  for (int j0 = 0; j0 < NPTS2; j0 += 64) {
    int j = j0 + lane;
    float d = distf(qn, m2x, m2y, m2z, p2x[j], p2y[j], p2z[j]);
    if (d <= T0) {
      int slot = atomicAdd(&cntS[wv], 1);
      if (slot < 64) { dbufS[wv][slot] = d; jbufS[wv][slot] = j; }
    }
  }
  __syncthreads();

  const int cnt = cntS[wv];
  if (cnt <= 64) {
    float dk = (lane < cnt) ? dbufS[wv][lane] : 3.402823466e38f;
    int   jk = (lane < cnt) ? jbufS[wv][lane] : 0x7fffffff;
#pragma unroll
    for (int k = 2; k <= 64; k <<= 1) {
#pragma unroll
      for (int jj = k >> 1; jj >= 1; jj >>= 1) {
        float od = __shfl_xor(dk, jj);
        int   oj = __shfl_xor(jk, jj);
        bool mineSm = (dk < od) || (dk == od && jk < oj);
        bool up = ((lane & k) == 0);
        bool keepmin = (((lane & jj) == 0) == up);
        bool takeOther = (keepmin != mineSm);
        dk = takeOther ? od : dk;
        jk = takeOther ? oj : jk;
      }
    }
    if (lane < KNN) idxout[(b * NPTS + n) * KNN + lane] = jk;
  } else {
    float dl = 3.402823466e38f;
    int   il = 0;
    for (int j0 = 0; j0 < NPTS2; j0 += 64) {
      int j = j0 + lane;
      float d = distf(qn, m2x, m2y, m2z, p2x[j], p2y[j], p2z[j]);
      float T = rdlane(dl, 19);
      unsigned long long m = __ballot(d < T);
      while (m) {
        int src = __ffsll(m) - 1;
        m &= m - 1;
        float dd = rdlane(d, src);
        float T2 = rdlane(dl, 19);
        if (dd < T2) {
          int jj2 = j0 + src;
          float pd = __shfl_up(dl, 1);
          int   pi = __shfl_up(il, 1);
          if (dl > dd) {
            if (lane == 0 || pd <= dd) { dl = dd; il = jj2; }
            else                       { dl = pd; il = pi; }
          }
        }
      }
    }
    if (lane < KNN) idxout[(b * NPTS + n) * KNN + lane] = il;
  }
}

// ---------------------------------------------------------------------------
// pack_weights (unchanged): BN folded into weights/biases.
// ---------------------------------------------------------------------------
__global__ __launch_bounds__(256) void pack_weights(
    const float* __restrict__ aw1, const float* __restrict__ awt,
    const float* __restrict__ pw2,
    const float* __restrict__ ag,  const float* __restrict__ av,
    const float* __restrict__ abt2, const float* __restrict__ am,
    const float* __restrict__ abt,
    const float* __restrict__ pg,  const float* __restrict__ pv,
    const float* __restrict__ pbt, const float* __restrict__ pm,
    const float* __restrict__ ab1, const float* __restrict__ pb1,
    const float* __restrict__ pw1,
    _Float16* __restrict__ aw1h, _Float16* __restrict__ awtP,
    _Float16* __restrict__ pw2h, float* __restrict__ abtX,
    float* __restrict__ ab1f, float* __restrict__ pw1f,
    float* __restrict__ pb1f) {
  int i = blockIdx.x * 256 + threadIdx.x;
  if (i < 16384) {
    int j = i >> 6;
    float inv = ag[j] / sqrtf(av[j] + EPSF);
    aw1h[i] = (_Float16)(aw1[i] * inv);
  }
  if (i < 32768) {
    int orr = i >> 8, j = i & 255;
    awtP[i] = (_Float16)awt[j * 128 + orr];
  }
  if (i < 4096) pw2h[i] = (_Float16)pw2[i];
  if (i < 256) {
    float inv = ag[i] / sqrtf(av[i] + EPSF);
    ab1f[i] = ab1[i] * inv + (abt2[i] - am[i] * inv);
  }
  if (i < 192) {
    int hc = i / 3;
    float inv = pg[hc] / sqrtf(pv[hc] + EPSF);
    pw1f[i] = pw1[i] * inv;
  }
  if (i < 128) abtX[i] = abt[i >> 1];
  if (i < 64) {
    float inv = pg[i] / sqrtf(pv[i] + EPSF);
    pb1f[i] = pb1[i] * inv + (pbt[i] - pm[i] * inv);
  }
}

// ---------------------------------------------------------------------------
// attn_mfma (R10): R9 structure (26880 B LDS, quarter-split C/D) but
// __launch_bounds__(256,4) -- R9's (256,6) forced a 40-VGPR budget and
// spilled 800 MB of scratch (FETCH 350MB/WRITE 430MB). With the 128-VGPR cap
// the kernel compiles ~64 VGPR and the HW schedules up to 6 blocks/CU
// (LDS-bound) with zero spill.
// ---------------------------------------------------------------------------
#define SM_H1B   0
#define SM_HB    0
#define SM_ALQ   0
#define SM_PEL   9216
#define SM_LGC   9216
#define SM_SJ    17920
#define SM_VGB   18176

__global__ __launch_bounds__(256, 4) void attn_mfma(
    const float* __restrict__ q_t, const float* __restrict__ k_t,
    const float* __restrict__ v_t, const int* __restrict__ idx,
    const float* __restrict__ pos1, const float* __restrict__ pos2,
    const float* __restrict__ pw1f, const float* __restrict__ pb1f,
    const _Float16* __restrict__ pw2h, const float* __restrict__ pb2,
    const _Float16* __restrict__ aw1h, const float* __restrict__ ab1f,
    const _Float16* __restrict__ awtP, const float* __restrict__ abtX,
    float* __restrict__ agg) {
  __shared__ __align__(16) char smem[26880];
  const int b  = blockIdx.x / BPB;
  const int n0 = (blockIdx.x - b * BPB) * QPB;
  const int t  = threadIdx.x;
  const int lane = t & 63;
  const int w  = t >> 6;        // wave id
  const int r  = lane & 15;     // tile lane index
  const int q4 = lane >> 4;     // quad

  int* sj = (int*)(smem + SM_SJ);

  // Phase 0: neighbor indices (invalid cols -> 0)
  if (t < 64) {
    int col = t;
    int p = col / 20, kk = col - p * 20;
    int nq = n0 + p;
    int vI = 0;
    if (p < QPB && nq < NPTS) vI = idx[(b * NPTS + nq) * KNN + kk];
    sj[col] = vI;
  }
  __syncthreads();

  // Prefetch q/k/v gather rows into registers (hide global latency)
  const int colB = t & 63, cgB = t >> 6;
  const int pB = colB / 20;
  const bool okB = (pB < QPB) && (n0 + pB < NPTS);
  f32x4 qv4[4], kv4[4], vv4[4];
  {
    int jB  = sj[colB];
    int nqB = okB ? (n0 + pB) : 0;
    const float* qrow = q_t + ((size_t)(b * NPTS  + nqB)) * DIM + cgB * 16;
    const float* krow = k_t + ((size_t)(b * NPTS2 + jB))  * DIM + cgB * 16;
    const float* vrow = v_t + ((size_t)(b * NPTS2 + jB))  * DIM + cgB * 16;
#pragma unroll
    for (int u = 0; u < 4; ++u) {
      qv4[u] = *(const f32x4*)(qrow + u * 4);
      kv4[u] = *(const f32x4*)(krow + u * 4);
      vv4[u] = *(const f32x4*)(vrow + u * 4);
    }
  }

  // Phase 1: pos-MLP hidden (BN folded) -> h1B f16 [col][hc] stride 72
  {
    int col = t & 63, hg = t >> 6;
    int p = col / 20;
    int j = sj[col];
    bool okc = (p < QPB) && (n0 + p < NPTS);
    float p0 = 0.f, p1 = 0.f, p2 = 0.f;
    if (okc) {
      int nq = n0 + p;
      p0 = pos1[(b * 3 + 0) * NPTS + nq] - pos2[(b * 3 + 0) * NPTS2 + j];
      p1 = pos1[(b * 3 + 1) * NPTS + nq] - pos2[(b * 3 + 1) * NPTS2 + j];
      p2 = pos1[(b * 3 + 2) * NPTS + nq] - pos2[(b * 3 + 2) * NPTS2 + j];
    }
#pragma unroll
    for (int ii = 0; ii < 16; ii += 2) {
      int hc = hg * 16 + ii;
      float v0 = pb1f[hc]     + pw1f[hc*3]   * p0 + pw1f[hc*3+1] * p1 + pw1f[hc*3+2] * p2;
      float v1 = pb1f[hc + 1] + pw1f[hc*3+3] * p0 + pw1f[hc*3+4] * p1 + pw1f[hc*3+5] * p2;
      v0 = fmaxf(v0, 0.f);
      v1 = fmaxf(v1, 0.f);
      if (!okc) { v0 = 0.f; v1 = 0.f; }
      h16x2 pk = {(_Float16)v0, (_Float16)v1};
      *(h16x2*)(smem + SM_H1B + ((col * 72 + hc) * 2)) = pk;
    }
  }
  __syncthreads();

  // Phase A: GEMM0 pe = pw2 @ h1 (+pb2) -> peL f16 [col][o] stride 68
  {
    h16x8 a0[2];
#pragma unroll
    for (int ks = 0; ks < 2; ++ks)
      a0[ks] = *(const h16x8*)&pw2h[(w * 16 + r) * 64 + ks * 32 + q4 * 8];
    f32x4 acc[4];
#pragma unroll
    for (int nt = 0; nt < 4; ++nt) acc[nt] = (f32x4){0.f, 0.f, 0.f, 0.f};
#pragma unroll
    for (int ks = 0; ks < 2; ++ks)
#pragma unroll
      for (int nt = 0; nt < 4; ++nt) {
        h16x8 bv = *(h16x8*)(smem + SM_H1B + ((nt * 16 + r) * 72 + ks * 32 + q4 * 8) * 2);
        acc[nt] = __builtin_amdgcn_mfma_f32_16x16x32_f16(a0[ks], bv, acc[nt], 0, 0, 0);
      }
    int o0 = w * 16 + q4 * 4;
    f32x4 pbv = *(const f32x4*)&pb2[o0];
#pragma unroll
    for (int nt = 0; nt < 4; ++nt) {
      f32x4 vv = acc[nt] + pbv;
      h16x4 pk = {(_Float16)vv[0], (_Float16)vv[1], (_Float16)vv[2], (_Float16)vv[3]};
      *(h16x4*)(smem + SM_PEL + ((nt * 16 + r) * 68 + o0) * 2) = pk;
    }
  }
  __syncthreads();

  // Phase B: combine prefetched q/k/v with pe -> hB (region0), vgB (f16)
  {
#pragma unroll
    for (int u = 0; u < 4; ++u) {
      int c0 = cgB * 16 + u * 4;
      h16x4 peh = *(h16x4*)(smem + SM_PEL + (colB * 68 + c0) * 2);
      f32x4 pe = {(float)peh[0], (float)peh[1], (float)peh[2], (float)peh[3]};
      f32x4 hv = qv4[u] - kv4[u] + pe;
      f32x4 gv = vv4[u] + pe;
      if (!okB) { hv = (f32x4){0.f,0.f,0.f,0.f}; gv = hv; }
      h16x4 hp = {(_Float16)hv[0], (_Float16)hv[1], (_Float16)hv[2], (_Float16)hv[3]};
      h16x4 gp = {(_Float16)gv[0], (_Float16)gv[1], (_Float16)gv[2], (_Float16)gv[3]};
      *(h16x4*)(smem + SM_HB  + (colB * 72 + c0) * 2) = hp;
      *(h16x4*)(smem + SM_VGB + (colB * 68 + c0) * 2) = gp;
    }
  }
  __syncthreads();

  // bs register load: h fragments (B-operand) for all 4 col tiles
  h16x8 bs[2][4];
#pragma unroll
  for (int ks = 0; ks < 2; ++ks)
#pragma unroll
    for (int nt = 0; nt < 4; ++nt)
      bs[ks][nt] = *(h16x8*)(smem + SM_HB + ((nt * 16 + r) * 72 + ks * 32 + q4 * 8) * 2);
  __syncthreads();   // hB fully consumed; region0 free for aLq

  // Phases C+D over four j-quarters (64 j's each). D accumulators in regs.
  f32x4 accD[2][4];
#pragma unroll
  for (int h = 0; h < 2; ++h)
#pragma unroll
    for (int nt = 0; nt < 4; ++nt) accD[h][nt] = (f32x4){0.f, 0.f, 0.f, 0.f};

#pragma unroll
  for (int quar = 0; quar < 4; ++quar) {
    // C-quarter: a = relu(aw1'@h + ab1'), 1 M-tile per wave
    {
      int mt = quar * 4 + w;
      h16x8 af0 = *(const h16x8*)&aw1h[(mt * 16 + r) * 64 + q4 * 8];
      h16x8 af1 = *(const h16x8*)&aw1h[(mt * 16 + r) * 64 + 32 + q4 * 8];
      f32x4 acc[4];
#pragma unroll
      for (int nt = 0; nt < 4; ++nt) acc[nt] = (f32x4){0.f, 0.f, 0.f, 0.f};
#pragma unroll
      for (int nt = 0; nt < 4; ++nt)
        acc[nt] = __builtin_amdgcn_mfma_f32_16x16x32_f16(af0, bs[0][nt], acc[nt], 0, 0, 0);
#pragma unroll
      for (int nt = 0; nt < 4; ++nt)
        acc[nt] = __builtin_amdgcn_mfma_f32_16x16x32_f16(af1, bs[1][nt], acc[nt], 0, 0, 0);
      int j0  = mt * 16 + q4 * 4;            // global j
      int jq0 = j0 - quar * 64;              // within quarter [0,64)
      f32x4 b1 = *(const f32x4*)&ab1f[j0];
#pragma unroll
      for (int nt = 0; nt < 4; ++nt) {
        int col = nt * 16 + r;
        float v0 = fmaxf(acc[nt][0] + b1[0], 0.f);
        float v1 = fmaxf(acc[nt][1] + b1[1], 0.f);
        float v2 = fmaxf(acc[nt][2] + b1[2], 0.f);
        float v3 = fmaxf(acc[nt][3] + b1[3], 0.f);
        h16x4 pk = {(_Float16)v0, (_Float16)v1, (_Float16)v2, (_Float16)v3};
        *(h16x4*)(smem + SM_ALQ + (col * 72 + jq0) * 2) = pk;
      }
    }
    __syncthreads();

    // D-quarter: accumulate logits over this quarter's K (2 x 32)
#pragma unroll
    for (int ks2 = 0; ks2 < 2; ++ks2) {
      h16x8 bsv[4];
#pragma unroll
      for (int nt = 0; nt < 4; ++nt)
        bsv[nt] = *(h16x8*)(smem + SM_ALQ + ((nt * 16 + r) * 72 + ks2 * 32 + q4 * 8) * 2);
      int ksg = quar * 2 + ks2;
#pragma unroll
      for (int h = 0; h < 2; ++h) {
        int mt2 = w * 2 + h;
        h16x8 af = *(const h16x8*)&awtP[(mt2 * 16 + r) * 256 + ksg * 32 + q4 * 8];
#pragma unroll
        for (int nt = 0; nt < 4; ++nt)
          accD[h][nt] = __builtin_amdgcn_mfma_f32_16x16x32_f16(af, bsv[nt], accD[h][nt], 0, 0, 0);
      }
    }
    __syncthreads();   // before next quarter's aLq rewrite
  }

  // Phase D epilogue + E: 2 half-rounds of (write lgc, softmax+agg)
  {
    const int li0 = w * 16 + q4 * 4;
#pragma unroll
    for (int h = 0; h < 2; ++h) {
      if (h) __syncthreads();   // E(h=0) done reading lgc
      int orr0 = (w * 2 + h) * 16 + q4 * 4;
      f32x4 ab = *(const f32x4*)&abtX[orr0];
#pragma unroll
      for (int nt = 0; nt < 4; ++nt) {
        int col = nt * 16 + r;
        if (col < QPB * KNN) {
          f32x4 vv = accD[h][nt] + ab;
          h16x4 pk = {(_Float16)vv[0], (_Float16)vv[1], (_Float16)vv[2], (_Float16)vv[3]};
          *(h16x4*)(smem + SM_LGC + (col * 68 + li0) * 2) = pk;
        }
      }
      __syncthreads();
      if (t < 64 * QPB) {
        int li = t & 63, p = t >> 6;
        if (n0 + p < NPTS) {
          int w2 = li >> 4;
          int orr = w2 * 32 + h * 16 + (li & 15);
          int o = orr >> 1, rb = orr & 1;
          float L[KNN];
#pragma unroll
          for (int kk = 0; kk < KNN; ++kk)
            L[kk] = (float)*(_Float16*)(smem + SM_LGC + (((p * 20 + kk) * 68 + li) * 2));
          float mx = L[0];
#pragma unroll
          for (int kk = 1; kk < KNN; ++kk) mx = fmaxf(mx, L[kk]);
          float s = 0.f;
#pragma unroll
          for (int kk = 0; kk < KNN; ++kk) { L[kk] = __expf(L[kk] - mx); s += L[kk]; }
          float rs = 1.0f / s;
          float a = 0.f;
#pragma unroll
          for (int kk = 0; kk < KNN; ++kk) {
            _Float16 gv = *(_Float16*)(smem + SM_VGB + (((p * 20 + kk) * 68 + o) * 2));
            a += L[kk] * (float)gv;
          }
          agg[(((size_t)(b * NPTS + n0 + p)) * UPF + rb) * DIM + o] = a * rs;
        }
      }
    }
  }
}

// ---------------------------------------------------------------------------
// out_proj (unchanged)
// ---------------------------------------------------------------------------
__global__ __launch_bounds__(256) void out_proj(const float* __restrict__ agg,
    const float* __restrict__ we, const float* __restrict__ be,
    const float* __restrict__ query, float* __restrict__ out) {
  __shared__ float A[64][65];
  const int b  = blockIdx.x >> 7;
  const int m0 = (blockIdx.x & 127) * 64;
  const int t  = threadIdx.x;
  for (int l = t; l < 64 * 64; l += 256) {
    int row = l >> 6, c = l & 63;
    A[row][c] = agg[(b * MOUT + m0 + row) * DIM + c];
  }
  __syncthreads();
  const int m_l = t & 63;
  const int w   = __builtin_amdgcn_readfirstlane(t >> 6);
  float acc[32];
#pragma unroll
  for (int i = 0; i < 32; ++i) acc[i] = 0.f;
  for (int c = 0; c < DIM; ++c) {
    float a = A[m_l][c];
#pragma unroll
    for (int i = 0; i < 32; ++i) acc[i] += we[(w * 32 + i) * DIM + c] * a;
  }
  const int m = m0 + m_l;
#pragma unroll
  for (int i = 0; i < 32; ++i) {
    int o = w * 32 + i;
    out[(b * CIN + o) * MOUT + m] = acc[i] + be[o] + query[(b * CIN + o) * NPTS + (m >> 1)];
  }
}

// ---------------------------------------------------------------------------
extern "C" void kernel_launch(void* const* d_in, const int* in_sizes, int n_in,
                              void* d_out, int out_size, void* d_ws, size_t ws_size,
                              hipStream_t stream) {
  (void)in_sizes; (void)n_in; (void)out_size; (void)ws_size;
  const float* pos1     = (const float*)d_in[0];
  const float* query    = (const float*)d_in[1];
  const float* pos2     = (const float*)d_in[2];
  const float* key_feat = (const float*)d_in[3];
  const float* wq  = (const float*)d_in[4];
  const float* bq  = (const float*)d_in[5];
  const float* wk  = (const float*)d_in[6];
  const float* bk  = (const float*)d_in[7];
  const float* wv  = (const float*)d_in[8];
  const float* bv  = (const float*)d_in[9];
  const float* pw1 = (const float*)d_in[10];
  const float* pb1 = (const float*)d_in[11];
  const float* pg  = (const float*)d_in[12];
  const float* pbt = (const float*)d_in[13];
  const float* pm  = (const float*)d_in[14];
  const float* pv  = (const float*)d_in[15];
  const float* pw2 = (const float*)d_in[16];
  const float* pb2 = (const float*)d_in[17];
  const float* aw1 = (const float*)d_in[18];
  const float* ab1 = (const float*)d_in[19];
  const float* ag  = (const float*)d_in[20];
  const float* abt2= (const float*)d_in[21];
  const float* am  = (const float*)d_in[22];
  const float* av  = (const float*)d_in[23];
  const float* awt = (const float*)d_in[24];
  const float* abt = (const float*)d_in[25];
  const float* we  = (const float*)d_in[26];
  const float* be  = (const float*)d_in[27];

  float* ws   = (float*)d_ws;
  float* q_t  = ws;
  float* k_t  = q_t + BATCH * NPTS * DIM;
  float* v_t  = k_t + BATCH * NPTS2 * DIM;
  float* aggb = v_t + BATCH * NPTS2 * DIM;
  int*   idxb = (int*)(aggb + BATCH * MOUT * DIM);
  _Float16* aw1h = (_Float16*)(idxb + BATCH * NPTS * KNN);
  _Float16* awtP = aw1h + HATT * DIM;
  _Float16* pw2h = awtP + 128 * HATT;
  float* abtX    = (float*)(pw2h + DIM * HPOS);
  float* ab1f    = abtX + 128;
  float* pw1f    = ab1f + HATT;
  float* pb1f    = pw1f + HPOS * 3;

  pack_weights<<<128, 256, 0, stream>>>(aw1, awt, pw2, ag, av, abt2, am, abt,
      pg, pv, pbt, pm, ab1, pb1, pw1,
      aw1h, awtP, pw2h, abtX, ab1f, pw1f, pb1f);
  proj_q <<<BATCH * (NPTS / 64), 256, 0, stream>>>(query, wq, bq, q_t);
  proj_kv<<<BATCH * (NPTS2 / 64), 256, 0, stream>>>(key_feat, wk, bk, wv, bv, k_t, v_t);
  knn_kernel<<<BATCH * NPTS / 4, 256, 0, stream>>>(pos1, pos2, idxb);
  attn_mfma<<<BATCH * BPB, 256, 0, stream>>>(q_t, k_t, v_t, idxb, pos1, pos2,
      pw1f, pb1f, pw2h, pb2, aw1h, ab1f, awtP, abtX, aggb);
  out_proj<<<BATCH * (MOUT / 64), 256, 0, stream>>>(aggb, we, be, query, (float*)d_out);
}

// Round 11
// 381.900 us; speedup vs baseline: 1.2787x; 1.0068x over previous
//
#include <hip/hip_runtime.h>
#include <hip/hip_bf16.h>

#define BATCH 4
#define NPTS  4096
#define NPTS2 4096
#define CIN   128
#define DIM   64
#define KNN   20
#define UPF   2
#define HPOS  64
#define HATT  256
#define MOUT  8192
#define EPSF  1e-5f
#define QPB   3            // queries per attn block
#define BPB   1366         // ceil(4096/3) attn blocks per batch

typedef _Float16 h16x8 __attribute__((ext_vector_type(8)));
typedef _Float16 h16x4 __attribute__((ext_vector_type(4)));
typedef _Float16 h16x2 __attribute__((ext_vector_type(2)));
typedef float    f32x4 __attribute__((ext_vector_type(4)));

__device__ inline float rdlane(float v, int src) {
  return __int_as_float(__builtin_amdgcn_readlane(__float_as_int(v), src));
}

// Bit-exact distance: explicit fma DAG -> identical value in every use site.
__device__ __forceinline__ float distf(float qn, float m2x, float m2y, float m2z,
                                       float x, float y, float z) {
  float s = __fmaf_rn(x, x, qn);
  s = __fmaf_rn(y, y, s);
  s = __fmaf_rn(z, z, s);
  s = __fmaf_rn(m2x, x, s);
  s = __fmaf_rn(m2y, y, s);
  s = __fmaf_rn(m2z, z, s);
  return s;
}

// ---------------------------------------------------------------------------
// proj_q (unchanged)
// ---------------------------------------------------------------------------
__global__ __launch_bounds__(256) void proj_q(const float* __restrict__ x,
    const float* __restrict__ wq, const float* __restrict__ bq,
    float* __restrict__ q_t) {
  __shared__ float X[CIN][64];
  __shared__ float O[64][65];
  const int b  = blockIdx.x >> 6;
  const int n0 = (blockIdx.x & 63) * 64;
  const int t  = threadIdx.x;
  for (int l = t; l < CIN * 64; l += 256) {
    int c = l >> 6, i = l & 63;
    X[c][i] = x[(b * CIN + c) * NPTS + n0 + i];
  }
  __syncthreads();
  const int n_l = t & 63;
  const int w   = __builtin_amdgcn_readfirstlane(t >> 6);
  float acc[16];
#pragma unroll
  for (int i = 0; i < 16; ++i) acc[i] = bq[w * 16 + i];
  for (int c = 0; c < CIN; ++c) {
    float xv = X[c][n_l];
#pragma unroll
    for (int i = 0; i < 16; ++i) acc[i] += wq[(w * 16 + i) * CIN + c] * xv;
  }
#pragma unroll
  for (int i = 0; i < 16; ++i) O[n_l][w * 16 + i] = acc[i];
  __syncthreads();
  for (int l = t; l < 64 * 64; l += 256)
    q_t[(b * NPTS + n0 + (l >> 6)) * DIM + (l & 63)] = O[l >> 6][l & 63];
}

// ---------------------------------------------------------------------------
// proj_kv (unchanged)
// ---------------------------------------------------------------------------
__global__ __launch_bounds__(256) void proj_kv(const float* __restrict__ x,
    const float* __restrict__ wk, const float* __restrict__ bk,
    const float* __restrict__ wv, const float* __restrict__ bv,
    float* __restrict__ k_t, float* __restrict__ v_t) {
  __shared__ float X[CIN][64];
  __shared__ float O[64][65];
  const int b  = blockIdx.x >> 6;
  const int n0 = (blockIdx.x & 63) * 64;
  const int t  = threadIdx.x;
  for (int l = t; l < CIN * 64; l += 256) {
    int c = l >> 6, i = l & 63;
    X[c][i] = x[(b * CIN + c) * NPTS2 + n0 + i];
  }
  __syncthreads();
  const int n_l = t & 63;
  const int w   = __builtin_amdgcn_readfirstlane(t >> 6);
  float acck[16], accv[16];
#pragma unroll
  for (int i = 0; i < 16; ++i) { acck[i] = bk[w * 16 + i]; accv[i] = bv[w * 16 + i]; }
  for (int c = 0; c < CIN; ++c) {
    float xv = X[c][n_l];
#pragma unroll
    for (int i = 0; i < 16; ++i) {
      acck[i] += wk[(w * 16 + i) * CIN + c] * xv;
      accv[i] += wv[(w * 16 + i) * CIN + c] * xv;
    }
  }
#pragma unroll
  for (int i = 0; i < 16; ++i) O[n_l][w * 16 + i] = acck[i];
  __syncthreads();
  for (int l = t; l < 64 * 64; l += 256)
    k_t[(b * NPTS2 + n0 + (l >> 6)) * DIM + (l & 63)] = O[l >> 6][l & 63];
  __syncthreads();
#pragma unroll
  for (int i = 0; i < 16; ++i) O[n_l][w * 16 + i] = accv[i];
  __syncthreads();
  for (int l = t; l < 64 * 64; l += 256)
    v_t[(b * NPTS2 + n0 + (l >> 6)) * DIM + (l & 63)] = O[l >> 6][l & 63];
}

// ---------------------------------------------------------------------------
// knn v4 (unchanged): threshold + LDS append + bitonic pair sort.
// ---------------------------------------------------------------------------
__global__ __launch_bounds__(256) void knn_kernel(const float* __restrict__ pos1,
    const float* __restrict__ pos2, int* __restrict__ idxout) {
  __shared__ int   cntS[4];
  __shared__ float dbufS[4][64];
  __shared__ int   jbufS[4][64];
  const int lane = threadIdx.x & 63;
  const int wv   = threadIdx.x >> 6;
  const int g    = blockIdx.x * 4 + wv;
  const int b    = g >> 12;
  const int n    = g & (NPTS - 1);
  const float qx = pos1[(b * 3 + 0) * NPTS + n];
  const float qy = pos1[(b * 3 + 1) * NPTS + n];
  const float qz = pos1[(b * 3 + 2) * NPTS + n];
  const float qn = qx * qx + qy * qy + qz * qz;
  const float m2x = -2.0f * qx, m2y = -2.0f * qy, m2z = -2.0f * qz;
  const float* p2x = pos2 + (b * 3 + 0) * NPTS2;
  const float* p2y = pos2 + (b * 3 + 1) * NPTS2;
  const float* p2z = pos2 + (b * 3 + 2) * NPTS2;

  float mymin = 3.402823466e38f;
  for (int j0 = 0; j0 < NPTS2; j0 += 64) {
    int j = j0 + lane;
    float d = distf(qn, m2x, m2y, m2z, p2x[j], p2y[j], p2z[j]);
    mymin = fminf(mymin, d);
  }
  float v = mymin;
#pragma unroll
  for (int k = 2; k <= 64; k <<= 1) {
#pragma unroll
    for (int jj = k >> 1; jj >= 1; jj >>= 1) {
      float o = __shfl_xor(v, jj);
      bool up = ((lane & k) == 0);
      bool keepmin = (((lane & jj) == 0) == up);
      v = keepmin ? fminf(v, o) : fmaxf(v, o);
    }
  }
  const float T0 = rdlane(v, 19);

  if (lane == 0) cntS[wv] = 0;
  __syncthreads();

  for (int j0 = 0; j0 < NPTS2; j0 += 64) {
    int j = j0 + lane;
    float d = distf(qn, m2x, m2y, m2z, p2x[j], p2y[j], p2z[j]);
    if (d <= T0) {
      int slot = atomicAdd(&cntS[wv], 1);
      if (slot < 64) { dbufS[wv][slot] = d; jbufS[wv][slot] = j; }
    }
  }
  __syncthreads();

  const int cnt = cntS[wv];
  if (cnt <= 64) {
    float dk = (lane < cnt) ? dbufS[wv][lane] : 3.402823466e38f;
    int   jk = (lane < cnt) ? jbufS[wv][lane] : 0x7fffffff;
#pragma unroll
    for (int k = 2; k <= 64; k <<= 1) {
#pragma unroll
      for (int jj = k >> 1; jj >= 1; jj >>= 1) {
        float od = __shfl_xor(dk, jj);
        int   oj = __shfl_xor(jk, jj);
        bool mineSm = (dk < od) || (dk == od && jk < oj);
        bool up = ((lane & k) == 0);
        bool keepmin = (((lane & jj) == 0) == up);
        bool takeOther = (keepmin != mineSm);
        dk = takeOther ? od : dk;
        jk = takeOther ? oj : jk;
      }
    }
    if (lane < KNN) idxout[(b * NPTS + n) * KNN + lane] = jk;
  } else {
    float dl = 3.402823466e38f;
    int   il = 0;
    for (int j0 = 0; j0 < NPTS2; j0 += 64) {
      int j = j0 + lane;
      float d = distf(qn, m2x, m2y, m2z, p2x[j], p2y[j], p2z[j]);
      float T = rdlane(dl, 19);
      unsigned long long m = __ballot(d < T);
      while (m) {
        int src = __ffsll(m) - 1;
        m &= m - 1;
        float dd = rdlane(d, src);
        float T2 = rdlane(dl, 19);
        if (dd < T2) {
          int jj2 = j0 + src;
          float pd = __shfl_up(dl, 1);
          int   pi = __shfl_up(il, 1);
          if (dl > dd) {
            if (lane == 0 || pd <= dd) { dl = dd; il = jj2; }
            else                       { dl = pd; il = pi; }
          }
        }
      }
    }
    if (lane < KNN) idxout[(b * NPTS + n) * KNN + lane] = il;
  }
}

// ---------------------------------------------------------------------------
// pack_weights (unchanged): BN folded into weights/biases.
// ---------------------------------------------------------------------------
__global__ __launch_bounds__(256) void pack_weights(
    const float* __restrict__ aw1, const float* __restrict__ awt,
    const float* __restrict__ pw2,
    const float* __restrict__ ag,  const float* __restrict__ av,
    const float* __restrict__ abt2, const float* __restrict__ am,
    const float* __restrict__ abt,
    const float* __restrict__ pg,  const float* __restrict__ pv,
    const float* __restrict__ pbt, const float* __restrict__ pm,
    const float* __restrict__ ab1, const float* __restrict__ pb1,
    const float* __restrict__ pw1,
    _Float16* __restrict__ aw1h, _Float16* __restrict__ awtP,
    _Float16* __restrict__ pw2h, float* __restrict__ abtX,
    float* __restrict__ ab1f, float* __restrict__ pw1f,
    float* __restrict__ pb1f) {
  int i = blockIdx.x * 256 + threadIdx.x;
  if (i < 16384) {
    int j = i >> 6;
    float inv = ag[j] / sqrtf(av[j] + EPSF);
    aw1h[i] = (_Float16)(aw1[i] * inv);
  }
  if (i < 32768) {
    int orr = i >> 8, j = i & 255;
    awtP[i] = (_Float16)awt[j * 128 + orr];
  }
  if (i < 4096) pw2h[i] = (_Float16)pw2[i];
  if (i < 256) {
    float inv = ag[i] / sqrtf(av[i] + EPSF);
    ab1f[i] = ab1[i] * inv + (abt2[i] - am[i] * inv);
  }
  if (i < 192) {
    int hc = i / 3;
    float inv = pg[hc] / sqrtf(pv[hc] + EPSF);
    pw1f[i] = pw1[i] * inv;
  }
  if (i < 128) abtX[i] = abt[i >> 1];
  if (i < 64) {
    float inv = pg[i] / sqrtf(pv[i] + EPSF);
    pb1f[i] = pb1[i] * inv + (pbt[i] - pm[i] * inv);
  }
}

// ---------------------------------------------------------------------------
// attn_mfma (R11): 7-barrier pipeline. Wave-ownership analysis:
//  - A->B: wave w writes peL ch [16w,16w+16) for all cols; B thread (colB,
//    cgB=w) reads exactly that range -> same wave, per-wave in-order LDS,
//    NO barrier (property validated by R6's correct wave-private arenas).
//  - hB overwrites peL IN PLACE (same thread, same element) -> R1 stable
//    through C/D, bs register load needs no trailing barrier.
//  - aLq double-buffered (R0 / BUF1): 1 barrier per quarter (D(q-1) || C(q)).
//  - sj LDS eliminated (each thread loads its own idx; L1-cached).
//  - lgc full-width 64x136 f16 over R0+R1 (dead after bar4): one write+one E.
// LDS map: R0 [0,9216) h1B/aLq-even; R1 [9216,18432) peL->hB(in place);
//          BUF1 [18432,27648) aLq-odd; lgc [0,17408) (post C/D);
//          VGB [27648,36352) 64x68 f16. Total 36352 B -> 4 blocks/CU.
// ---------------------------------------------------------------------------
#define SM_R0    0
#define SM_R1    9216
#define SM_BUF1  18432
#define SM_LGC   0
#define SM_VGB   27648

__global__ __launch_bounds__(256, 4) void attn_mfma(
    const float* __restrict__ q_t, const float* __restrict__ k_t,
    const float* __restrict__ v_t, const int* __restrict__ idx,
    const float* __restrict__ pos1, const float* __restrict__ pos2,
    const float* __restrict__ pw1f, const float* __restrict__ pb1f,
    const _Float16* __restrict__ pw2h, const float* __restrict__ pb2,
    const _Float16* __restrict__ aw1h, const float* __restrict__ ab1f,
    const _Float16* __restrict__ awtP, const float* __restrict__ abtX,
    float* __restrict__ agg) {
  __shared__ __align__(16) char smem[36352];
  const int b  = blockIdx.x / BPB;
  const int n0 = (blockIdx.x - b * BPB) * QPB;
  const int t  = threadIdx.x;
  const int lane = t & 63;
  const int w  = t >> 6;        // wave id
  const int r  = lane & 15;     // tile lane index
  const int q4 = lane >> 4;     // quad

  // Per-thread neighbor index (no sj LDS; redundant x4, L1-cached)
  const int colB = t & 63, cgB = t >> 6;
  const int pB = colB / 20, kkB = colB - pB * 20;
  const bool okB = (pB < QPB) && (n0 + pB < NPTS);
  const int nqB = okB ? (n0 + pB) : 0;
  int jB = 0;
  if (okB) jB = idx[(b * NPTS + nqB) * KNN + kkB];

  // Prefetch q/k/v gather rows into registers (hide global latency)
  f32x4 qv4[4], kv4[4], vv4[4];
  {
    const float* qrow = q_t + ((size_t)(b * NPTS  + nqB)) * DIM + cgB * 16;
    const float* krow = k_t + ((size_t)(b * NPTS2 + jB))  * DIM + cgB * 16;
    const float* vrow = v_t + ((size_t)(b * NPTS2 + jB))  * DIM + cgB * 16;
#pragma unroll
    for (int u = 0; u < 4; ++u) {
      qv4[u] = *(const f32x4*)(qrow + u * 4);
      kv4[u] = *(const f32x4*)(krow + u * 4);
      vv4[u] = *(const f32x4*)(vrow + u * 4);
    }
  }

  // Phase 1: pos-MLP hidden (BN folded) -> h1B f16 [col][hc] stride 72 (R0)
  {
    float p0 = 0.f, p1 = 0.f, p2 = 0.f;
    if (okB) {
      p0 = pos1[(b * 3 + 0) * NPTS + nqB] - pos2[(b * 3 + 0) * NPTS2 + jB];
      p1 = pos1[(b * 3 + 1) * NPTS + nqB] - pos2[(b * 3 + 1) * NPTS2 + jB];
      p2 = pos1[(b * 3 + 2) * NPTS + nqB] - pos2[(b * 3 + 2) * NPTS2 + jB];
    }
#pragma unroll
    for (int ii = 0; ii < 16; ii += 2) {
      int hc = cgB * 16 + ii;
      float v0 = pb1f[hc]     + pw1f[hc*3]   * p0 + pw1f[hc*3+1] * p1 + pw1f[hc*3+2] * p2;
      float v1 = pb1f[hc + 1] + pw1f[hc*3+3] * p0 + pw1f[hc*3+4] * p1 + pw1f[hc*3+5] * p2;
      v0 = fmaxf(v0, 0.f);
      v1 = fmaxf(v1, 0.f);
      if (!okB) { v0 = 0.f; v1 = 0.f; }
      h16x2 pk = {(_Float16)v0, (_Float16)v1};
      *(h16x2*)(smem + SM_R0 + ((colB * 72 + hc) * 2)) = pk;
    }
  }
  __syncthreads();   // bar 1: h1B cross-wave for A

  // Phase A: GEMM0 pe = pw2 @ h1 (+pb2) -> peL f16 [col][o] stride 72 (R1)
  {
    h16x8 a0[2];
#pragma unroll
    for (int ks = 0; ks < 2; ++ks)
      a0[ks] = *(const h16x8*)&pw2h[(w * 16 + r) * 64 + ks * 32 + q4 * 8];
    f32x4 acc[4];
#pragma unroll
    for (int nt = 0; nt < 4; ++nt) acc[nt] = (f32x4){0.f, 0.f, 0.f, 0.f};
#pragma unroll
    for (int ks = 0; ks < 2; ++ks)
#pragma unroll
      for (int nt = 0; nt < 4; ++nt) {
        h16x8 bv = *(h16x8*)(smem + SM_R0 + ((nt * 16 + r) * 72 + ks * 32 + q4 * 8) * 2);
        acc[nt] = __builtin_amdgcn_mfma_f32_16x16x32_f16(a0[ks], bv, acc[nt], 0, 0, 0);
      }
    int o0 = w * 16 + q4 * 4;
    f32x4 pbv = *(const f32x4*)&pb2[o0];
#pragma unroll
    for (int nt = 0; nt < 4; ++nt) {
      f32x4 vv = acc[nt] + pbv;
      h16x4 pk = {(_Float16)vv[0], (_Float16)vv[1], (_Float16)vv[2], (_Float16)vv[3]};
      *(h16x4*)(smem + SM_R1 + ((nt * 16 + r) * 72 + o0) * 2) = pk;
    }
  }
  // NO barrier: wave w wrote peL ch [16w,16w+16) for all cols; B's thread
  // (colB, cgB=w) reads only that range. Per-wave LDS is in-order.

  // Phase B: h = q-kg+pe IN PLACE over peL (R1); vg -> vgB stride 68
  {
#pragma unroll
    for (int u = 0; u < 4; ++u) {
      int c0 = cgB * 16 + u * 4;
      h16x4 peh = *(h16x4*)(smem + SM_R1 + (colB * 72 + c0) * 2);
      f32x4 pe = {(float)peh[0], (float)peh[1], (float)peh[2], (float)peh[3]};
      f32x4 hv = qv4[u] - kv4[u] + pe;
      f32x4 gv = vv4[u] + pe;
      if (!okB) { hv = (f32x4){0.f,0.f,0.f,0.f}; gv = hv; }
      h16x4 hp = {(_Float16)hv[0], (_Float16)hv[1], (_Float16)hv[2], (_Float16)hv[3]};
      h16x4 gp = {(_Float16)gv[0], (_Float16)gv[1], (_Float16)gv[2], (_Float16)gv[3]};
      *(h16x4*)(smem + SM_R1  + (colB * 72 + c0) * 2) = hp;
      *(h16x4*)(smem + SM_VGB + (colB * 68 + c0) * 2) = gp;
    }
  }
  __syncthreads();   // bar 2: hB cross-wave + WAR on R0 (aLq)

  // bs register load from hB (R1, stable through C/D -> no barrier after)
  h16x8 bs[2][4];
#pragma unroll
  for (int ks = 0; ks < 2; ++ks)
#pragma unroll
    for (int nt = 0; nt < 4; ++nt)
      bs[ks][nt] = *(h16x8*)(smem + SM_R1 + ((nt * 16 + r) * 72 + ks * 32 + q4 * 8) * 2);

  // Phases C+D over four j-quarters, double-buffered aLq (R0 / BUF1).
  f32x4 accD[2][4];
#pragma unroll
  for (int h = 0; h < 2; ++h)
#pragma unroll
    for (int nt = 0; nt < 4; ++nt) accD[h][nt] = (f32x4){0.f, 0.f, 0.f, 0.f};

#define C_QUARTER(quar, base)                                                  \
  {                                                                            \
    int mt = (quar) * 4 + w;                                                   \
    h16x8 af0 = *(const h16x8*)&aw1h[(mt * 16 + r) * 64 + q4 * 8];             \
    h16x8 af1 = *(const h16x8*)&aw1h[(mt * 16 + r) * 64 + 32 + q4 * 8];        \
    f32x4 acc[4];                                                              \
    _Pragma("unroll")                                                          \
    for (int nt = 0; nt < 4; ++nt) acc[nt] = (f32x4){0.f, 0.f, 0.f, 0.f};      \
    _Pragma("unroll")                                                          \
    for (int nt = 0; nt < 4; ++nt)                                             \
      acc[nt] = __builtin_amdgcn_mfma_f32_16x16x32_f16(af0, bs[0][nt], acc[nt], 0, 0, 0); \
    _Pragma("unroll")                                                          \
    for (int nt = 0; nt < 4; ++nt)                                             \
      acc[nt] = __builtin_amdgcn_mfma_f32_16x16x32_f16(af1, bs[1][nt], acc[nt], 0, 0, 0); \
    int j0  = mt * 16 + q4 * 4;                                                \
    int jq0 = j0 - (quar) * 64;                                                \
    f32x4 b1 = *(const f32x4*)&ab1f[j0];                                       \
    _Pragma("unroll")                                                          \
    for (int nt = 0; nt < 4; ++nt) {                                           \
      int col = nt * 16 + r;                                                   \
      float v0 = fmaxf(acc[nt][0] + b1[0], 0.f);                               \
      float v1 = fmaxf(acc[nt][1] + b1[1], 0.f);                               \
      float v2 = fmaxf(acc[nt][2] + b1[2], 0.f);                               \
      float v3 = fmaxf(acc[nt][3] + b1[3], 0.f);                               \
      h16x4 pk = {(_Float16)v0, (_Float16)v1, (_Float16)v2, (_Float16)v3};     \
      *(h16x4*)(smem + (base) + (col * 72 + jq0) * 2) = pk;                    \
    }                                                                          \
  }

#define D_QUARTER(quar, base)                                                  \
  {                                                                            \
    _Pragma("unroll")                                                          \
    for (int ks2 = 0; ks2 < 2; ++ks2) {                                        \
      h16x8 bsv[4];                                                            \
      _Pragma("unroll")                                                        \
      for (int nt = 0; nt < 4; ++nt)                                           \
        bsv[nt] = *(h16x8*)(smem + (base) + ((nt * 16 + r) * 72 + ks2 * 32 + q4 * 8) * 2); \
      int ksg = (quar) * 2 + ks2;                                              \
      _Pragma("unroll")                                                        \
      for (int h = 0; h < 2; ++h) {                                            \
        int mt2 = w * 2 + h;                                                   \
        h16x8 af = *(const h16x8*)&awtP[(mt2 * 16 + r) * 256 + ksg * 32 + q4 * 8]; \
        _Pragma("unroll")                                                      \
        for (int nt = 0; nt < 4; ++nt)                                         \
          accD[h][nt] = __builtin_amdgcn_mfma_f32_16x16x32_f16(af, bsv[nt], accD[h][nt], 0, 0, 0); \
      }                                                                        \
    }                                                                          \
  }

  C_QUARTER(0, SM_R0)
  __syncthreads();   // bar 3
  D_QUARTER(0, SM_R0)
  C_QUARTER(1, SM_BUF1)
  __syncthreads();   // bar 4
  D_QUARTER(1, SM_BUF1)
  C_QUARTER(2, SM_R0)
  __syncthreads();   // bar 5
  D_QUARTER(2, SM_R0)
  C_QUARTER(3, SM_BUF1)
  __syncthreads();   // bar 6
  D_QUARTER(3, SM_BUF1)

  // lgc write: full 64x136 f16 over R0+R1 (both dead; BUF1 untouched so
  // concurrent D3 stragglers are safe)
  {
#pragma unroll
    for (int h = 0; h < 2; ++h) {
      int orr0 = (w * 2 + h) * 16 + q4 * 4;
      f32x4 ab = *(const f32x4*)&abtX[orr0];
#pragma unroll
      for (int nt = 0; nt < 4; ++nt) {
        int col = nt * 16 + r;
        if (col < QPB * KNN) {
          f32x4 vv = accD[h][nt] + ab;
          h16x4 pk = {(_Float16)vv[0], (_Float16)vv[1], (_Float16)vv[2], (_Float16)vv[3]};
          *(h16x4*)(smem + SM_LGC + (col * 136 + orr0) * 2) = pk;
        }
      }
    }
  }
  __syncthreads();   // bar 7: lgc cross-wave for E

  // Phase E: softmax over k=20 + aggregation, both halves per thread
  if (t < 64 * QPB) {
    int li = t & 63, p = t >> 6;
    if (n0 + p < NPTS) {
#pragma unroll
      for (int half = 0; half < 2; ++half) {
        int orr = (li >> 4) * 32 + half * 16 + (li & 15);
        int o = orr >> 1, rb = orr & 1;
        float L[KNN];
#pragma unroll
        for (int kk = 0; kk < KNN; ++kk)
          L[kk] = (float)*(_Float16*)(smem + SM_LGC + (((p * 20 + kk) * 136 + orr) * 2));
        float mx = L[0];
#pragma unroll
        for (int kk = 1; kk < KNN; ++kk) mx = fmaxf(mx, L[kk]);
        float s = 0.f;
#pragma unroll
        for (int kk = 0; kk < KNN; ++kk) { L[kk] = __expf(L[kk] - mx); s += L[kk]; }
        float rs = 1.0f / s;
        float a = 0.f;
#pragma unroll
        for (int kk = 0; kk < KNN; ++kk) {
          _Float16 gv = *(_Float16*)(smem + SM_VGB + (((p * 20 + kk) * 68 + o) * 2));
          a += L[kk] * (float)gv;
        }
        agg[(((size_t)(b * NPTS + n0 + p)) * UPF + rb) * DIM + o] = a * rs;
      }
    }
  }
#undef C_QUARTER
#undef D_QUARTER
}

// ---------------------------------------------------------------------------
// out_proj (unchanged)
// ---------------------------------------------------------------------------
__global__ __launch_bounds__(256) void out_proj(const float* __restrict__ agg,
    const float* __restrict__ we, const float* __restrict__ be,
    const float* __restrict__ query, float* __restrict__ out) {
  __shared__ float A[64][65];
  const int b  = blockIdx.x >> 7;
  const int m0 = (blockIdx.x & 127) * 64;
  const int t  = threadIdx.x;
  for (int l = t; l < 64 * 64; l += 256) {
    int row = l >> 6, c = l & 63;
    A[row][c] = agg[(b * MOUT + m0 + row) * DIM + c];
  }
  __syncthreads();
  const int m_l = t & 63;
  const int w   = __builtin_amdgcn_readfirstlane(t >> 6);
  float acc[32];
#pragma unroll
  for (int i = 0; i < 32; ++i) acc[i] = 0.f;
  for (int c = 0; c < DIM; ++c) {
    float a = A[m_l][c];
#pragma unroll
    for (int i = 0; i < 32; ++i) acc[i] += we[(w * 32 + i) * DIM + c] * a;
  }
  const int m = m0 + m_l;
#pragma unroll
  for (int i = 0; i < 32; ++i) {
    int o = w * 32 + i;
    out[(b * CIN + o) * MOUT + m] = acc[i] + be[o] + query[(b * CIN + o) * NPTS + (m >> 1)];
  }
}

// ---------------------------------------------------------------------------
extern "C" void kernel_launch(void* const* d_in, const int* in_sizes, int n_in,
                              void* d_out, int out_size, void* d_ws, size_t ws_size,
                              hipStream_t stream) {
  (void)in_sizes; (void)n_in; (void)out_size; (void)ws_size;
  const float* pos1     = (const float*)d_in[0];
  const float* query    = (const float*)d_in[1];
  const float* pos2     = (const float*)d_in[2];
  const float* key_feat = (const float*)d_in[3];
  const float* wq  = (const float*)d_in[4];
  const float* bq  = (const float*)d_in[5];
  const float* wk  = (const float*)d_in[6];
  const float* bk  = (const float*)d_in[7];
  const float* wv  = (const float*)d_in[8];
  const float* bv  = (const float*)d_in[9];
  const float* pw1 = (const float*)d_in[10];
  const float* pb1 = (const float*)d_in[11];
  const float* pg  = (const float*)d_in[12];
  const float* pbt = (const float*)d_in[13];
  const float* pm  = (const float*)d_in[14];
  const float* pv  = (const float*)d_in[15];
  const float* pw2 = (const float*)d_in[16];
  const float* pb2 = (const float*)d_in[17];
  const float* aw1 = (const float*)d_in[18];
  const float* ab1 = (const float*)d_in[19];
  const float* ag  = (const float*)d_in[20];
  const float* abt2= (const float*)d_in[21];
  const float* am  = (const float*)d_in[22];
  const float* av  = (const float*)d_in[23];
  const float* awt = (const float*)d_in[24];
  const float* abt = (const float*)d_in[25];
  const float* we  = (const float*)d_in[26];
  const float* be  = (const float*)d_in[27];

  float* ws   = (float*)d_ws;
  float* q_t  = ws;
  float* k_t  = q_t + BATCH * NPTS * DIM;
  float* v_t  = k_t + BATCH * NPTS2 * DIM;
  float* aggb = v_t + BATCH * NPTS2 * DIM;
  int*   idxb = (int*)(aggb + BATCH * MOUT * DIM);
  _Float16* aw1h = (_Float16*)(idxb + BATCH * NPTS * KNN);
  _Float16* awtP = aw1h + HATT * DIM;
  _Float16* pw2h = awtP + 128 * HATT;
  float* abtX    = (float*)(pw2h + DIM * HPOS);
  float* ab1f    = abtX + 128;
  float* pw1f    = ab1f + HATT;
  float* pb1f    = pw1f + HPOS * 3;

  pack_weights<<<128, 256, 0, stream>>>(aw1, awt, pw2, ag, av, abt2, am, abt,
      pg, pv, pbt, pm, ab1, pb1, pw1,
      aw1h, awtP, pw2h, abtX, ab1f, pw1f, pb1f);
  proj_q <<<BATCH * (NPTS / 64), 256, 0, stream>>>(query, wq, bq, q_t);
  proj_kv<<<BATCH * (NPTS2 / 64), 256, 0, stream>>>(key_feat, wk, bk, wv, bv, k_t, v_t);
  knn_kernel<<<BATCH * NPTS / 4, 256, 0, stream>>>(pos1, pos2, idxb);
  attn_mfma<<<BATCH * BPB, 256, 0, stream>>>(q_t, k_t, v_t, idxb, pos1, pos2,
      pw1f, pb1f, pw2h, pb2, aw1h, ab1f, awtP, abtX, aggb);
  out_proj<<<BATCH * (MOUT / 64), 256, 0, stream>>>(aggb, we, be, query, (float*)d_out);
}